// Round 1
// baseline (340.863 us; speedup 1.0000x reference)
//
#include <hip/hip_runtime.h>

typedef unsigned short u16;
typedef __attribute__((ext_vector_type(8))) short bf16x8;
typedef __attribute__((ext_vector_type(4))) float f32x4;

// ---------- helpers ----------
__device__ __forceinline__ u16 f2b(float f) {
  unsigned u = __float_as_uint(f);
  u += 0x7FFFu + ((u >> 16) & 1u);   // round-to-nearest-even to bf16
  return (u16)(u >> 16);
}
__device__ __forceinline__ float sigm(float x) { return 1.0f / (1.0f + __expf(-x)); }
__device__ __forceinline__ float tanh_f(float x) { return 1.0f - 2.0f / (__expf(2.0f * x) + 1.0f); }

__device__ __forceinline__ void cp16(const u16* g, u16* l) {
  __builtin_amdgcn_global_load_lds(
      (const __attribute__((address_space(1))) unsigned int*)g,
      (__attribute__((address_space(3))) unsigned int*)l, 16, 0, 0);
}

// ---------- pack kernels ----------
// xhb[i][k] = bf16( k<1024 ? x[i][k] : h[i][k-1024] ), shape [8192][2048]
__global__ __launch_bounds__(256) void pack_xh(const float* __restrict__ x,
                                               const float* __restrict__ h,
                                               u16* __restrict__ xhb) {
  int idx = blockIdx.x * 256 + threadIdx.x;      // one float4 group
  int row = idx >> 9;                            // /512 groups per row (2048/4)
  int k = (idx & 511) << 2;
  const float* src = (k < 1024) ? (x + row * 1024 + k) : (h + row * 1024 + (k - 1024));
  float4 v = *reinterpret_cast<const float4*>(src);
  ushort4 o = make_ushort4(f2b(v.x), f2b(v.y), f2b(v.z), f2b(v.w));
  *reinterpret_cast<ushort4*>(xhb + ((size_t)idx << 2)) = o;
}

// W1b: [3072][2048] bf16. rows 0..1023: [Wwz|Wuz]; 1024..2047: [Wwr|Wur]; 2048..3071: [Ww|unused]
__global__ __launch_bounds__(256) void pack_w1(const float* __restrict__ Wwz,
                                               const float* __restrict__ Wuz,
                                               const float* __restrict__ Wwr,
                                               const float* __restrict__ Wur,
                                               const float* __restrict__ Ww,
                                               u16* __restrict__ W1b) {
  int idx = blockIdx.x * 256 + threadIdx.x;
  int n = idx >> 9;
  int k = (idx & 511) << 2;
  float4 v = make_float4(0.f, 0.f, 0.f, 0.f);
  if (n < 1024) {
    v = (k < 1024) ? *reinterpret_cast<const float4*>(Wwz + n * 1024 + k)
                   : *reinterpret_cast<const float4*>(Wuz + n * 1024 + (k - 1024));
  } else if (n < 2048) {
    int nn = n - 1024;
    v = (k < 1024) ? *reinterpret_cast<const float4*>(Wwr + nn * 1024 + k)
                   : *reinterpret_cast<const float4*>(Wur + nn * 1024 + (k - 1024));
  } else {
    int nn = n - 2048;
    if (k < 1024) v = *reinterpret_cast<const float4*>(Ww + nn * 1024 + k);
  }
  ushort4 o = make_ushort4(f2b(v.x), f2b(v.y), f2b(v.z), f2b(v.w));
  *reinterpret_cast<ushort4*>(W1b + ((size_t)idx << 2)) = o;
}

__global__ __launch_bounds__(256) void pack_wu(const float* __restrict__ Wu,
                                               u16* __restrict__ Wub) {
  int idx = blockIdx.x * 256 + threadIdx.x;     // 1024*1024/4 groups
  float4 v = *reinterpret_cast<const float4*>(Wu + ((size_t)idx << 2));
  ushort4 o = make_ushort4(f2b(v.x), f2b(v.y), f2b(v.z), f2b(v.w));
  *reinterpret_cast<ushort4*>(Wub + ((size_t)idx << 2)) = o;
}

// ---------- GEMM core: C[128x128] = A[128xK] * Bm[128xK]^T (both row-major, bf16) ----------
__device__ __forceinline__ void gemm_core(const u16* __restrict__ A, const u16* __restrict__ Bm,
                                          int lda, int ldb, int m0, int n0, int ksteps,
                                          u16* a_lds, u16* b_lds, f32x4 acc[4][4]) {
  const int tid = threadIdx.x;
  const int lane = tid & 63;
  const int wave = tid >> 6;
  const int wr = wave >> 1, wc = wave & 1;
  // staging: 256 threads x 16B covers 64 rows x 32 cols; two issues per tile
  const int srow = tid >> 2;
  const int scol = (tid & 3) << 3;
  const u16* ga = A + (size_t)(m0 + srow) * lda + scol;
  const u16* gb = Bm + (size_t)(n0 + srow) * ldb + scol;
  u16* la = a_lds + tid * 8;   // linear in tid: HW writes base+lane*16
  u16* lb = b_lds + tid * 8;
  // fragment read coords
  const int fr = lane & 15;
  const int fk = (lane >> 4) << 3;

  for (int kt = 0; kt < ksteps; ++kt) {
    const int k0 = kt * 32;
    cp16(ga + k0, la);
    cp16(ga + (size_t)64 * lda + k0, la + 64 * 32);
    cp16(gb + k0, lb);
    cp16(gb + (size_t)64 * ldb + k0, lb + 64 * 32);
    __syncthreads();   // compiler drains vmcnt before s_barrier

    bf16x8 af[4], bfr[4];
#pragma unroll
    for (int m = 0; m < 4; ++m)
      af[m] = *reinterpret_cast<const bf16x8*>(&a_lds[(wr * 64 + m * 16 + fr) * 32 + fk]);
#pragma unroll
    for (int n = 0; n < 4; ++n)
      bfr[n] = *reinterpret_cast<const bf16x8*>(&b_lds[(wc * 64 + n * 16 + fr) * 32 + fk]);
#pragma unroll
    for (int m = 0; m < 4; ++m)
#pragma unroll
      for (int n = 0; n < 4; ++n)
        acc[m][n] = __builtin_amdgcn_mfma_f32_16x16x32_bf16(af[m], bfr[n], acc[m][n], 0, 0, 0);
    __syncthreads();
  }
}

// GEMM1: [8192 x 3072] = xhb[8192x2048] @ W1b^T. Epilogue splits by column region.
__global__ __launch_bounds__(256) void gemm1_k(const u16* __restrict__ xhb,
                                               const u16* __restrict__ W1b,
                                               const float* __restrict__ h,
                                               float* __restrict__ zout,       // = d_out (temp)
                                               u16* __restrict__ rhb,
                                               float* __restrict__ xwb) {
  __shared__ u16 a_lds[128 * 32];
  __shared__ u16 b_lds[128 * 32];
  const int m0 = blockIdx.y * 128;
  const int n0 = blockIdx.x * 128;
  const int ksteps = (n0 >= 2048) ? 32 : 64;   // K=1024 for the W_w slice, else 2048
  f32x4 acc[4][4];
#pragma unroll
  for (int m = 0; m < 4; ++m)
#pragma unroll
    for (int n = 0; n < 4; ++n) acc[m][n] = (f32x4){0.f, 0.f, 0.f, 0.f};

  gemm_core(xhb, W1b, 2048, 2048, m0, n0, ksteps, a_lds, b_lds, acc);

  const int lane = threadIdx.x & 63;
  const int wave = threadIdx.x >> 6;
  const int wr = wave >> 1, wc = wave & 1;
  const int rbase = m0 + wr * 64 + ((lane >> 4) << 2);
  const int cbase = n0 + wc * 64 + (lane & 15);
  const int region = n0 >> 10;   // block-uniform: 0=z, 1=r, 2=w
#pragma unroll
  for (int m = 0; m < 4; ++m) {
#pragma unroll
    for (int n = 0; n < 4; ++n) {
      const int col = cbase + n * 16;
#pragma unroll
      for (int j = 0; j < 4; ++j) {
        const int row = rbase + m * 16 + j;
        const float v = acc[m][n][j];
        if (region == 0) {
          zout[(size_t)row * 1024 + col] = sigm(v);
        } else if (region == 1) {
          const size_t idx = (size_t)row * 1024 + (col - 1024);
          rhb[idx] = f2b(sigm(v) * h[idx]);
        } else {
          xwb[(size_t)row * 1024 + (col - 2048)] = v;
        }
      }
    }
  }
}

// GEMM2: C2 = rhb[8192x1024] @ Wub^T; out = z*h + (1-z)*tanh(C2 + xw)
__global__ __launch_bounds__(256) void gemm2_k(const u16* __restrict__ rhb,
                                               const u16* __restrict__ Wub,
                                               const float* __restrict__ h,
                                               const float* __restrict__ xwb,
                                               float* __restrict__ out) {  // holds z on entry
  __shared__ u16 a_lds[128 * 32];
  __shared__ u16 b_lds[128 * 32];
  const int m0 = blockIdx.y * 128;
  const int n0 = blockIdx.x * 128;
  f32x4 acc[4][4];
#pragma unroll
  for (int m = 0; m < 4; ++m)
#pragma unroll
    for (int n = 0; n < 4; ++n) acc[m][n] = (f32x4){0.f, 0.f, 0.f, 0.f};

  gemm_core(rhb, Wub, 1024, 1024, m0, n0, 32, a_lds, b_lds, acc);

  const int lane = threadIdx.x & 63;
  const int wave = threadIdx.x >> 6;
  const int wr = wave >> 1, wc = wave & 1;
  const int rbase = m0 + wr * 64 + ((lane >> 4) << 2);
  const int cbase = n0 + wc * 64 + (lane & 15);
#pragma unroll
  for (int m = 0; m < 4; ++m) {
#pragma unroll
    for (int n = 0; n < 4; ++n) {
      const int col = cbase + n * 16;
#pragma unroll
      for (int j = 0; j < 4; ++j) {
        const int row = rbase + m * 16 + j;
        const size_t idx = (size_t)row * 1024 + col;
        const float z = out[idx];
        const float hv = h[idx];
        const float ht = tanh_f(acc[m][n][j] + xwb[idx]);
        out[idx] = z * hv + (1.0f - z) * ht;
      }
    }
  }
}

// ---------- launch ----------
extern "C" void kernel_launch(void* const* d_in, const int* in_sizes, int n_in,
                              void* d_out, int out_size, void* d_ws, size_t ws_size,
                              hipStream_t stream) {
  const float* x   = (const float*)d_in[0];
  const float* h   = (const float*)d_in[1];
  const float* Wwz = (const float*)d_in[2];
  const float* Wuz = (const float*)d_in[3];
  const float* Wwr = (const float*)d_in[4];
  const float* Wur = (const float*)d_in[5];
  const float* Wu  = (const float*)d_in[6];
  const float* Ww  = (const float*)d_in[7];
  float* out = (float*)d_out;

  char* ws = (char*)d_ws;
  u16*   xhb = (u16*)(ws);                      // 8192*2048*2 = 33,554,432
  u16*   W1b = (u16*)(ws + 33554432);           // 3072*2048*2 = 12,582,912
  u16*   Wub = (u16*)(ws + 46137344);           // 1024*1024*2 =  2,097,152
  u16*   rhb = (u16*)(ws + 48234496);           // 8192*1024*2 = 16,777,216
  float* xwb = (float*)(ws + 65011712);         // 8192*1024*4 = 33,554,432  (total 98,566,144)

  pack_xh<<<16384, 256, 0, stream>>>(x, h, xhb);
  pack_w1<<<6144, 256, 0, stream>>>(Wwz, Wuz, Wwr, Wur, Ww, W1b);
  pack_wu<<<1024, 256, 0, stream>>>(Wu, Wub);
  gemm1_k<<<dim3(24, 64), 256, 0, stream>>>(xhb, W1b, h, out, rhb, xwb);
  gemm2_k<<<dim3(8, 64), 256, 0, stream>>>(rhb, Wub, h, xwb, out);
}